// Round 6
// baseline (200.795 us; speedup 1.0000x reference)
//
#include <hip/hip_runtime.h>
#include <stdint.h>

#define NROWS 65536
#define DIM   256
#define NC    1024
#define NO    64

#define BN    64           // rows per block (4 waves x 16 rows)
#define WROWS 16           // rows per wave
#define BC    64           // centers per tile
#define NTILE (NC / BC)    // 16

using bf16x8 = __bf16 __attribute__((ext_vector_type(8)));
using f32x4  = float __attribute__((ext_vector_type(4)));
using u16x4  = unsigned short __attribute__((ext_vector_type(4)));
using u32x2  = unsigned int __attribute__((ext_vector_type(2)));

#define MFMA16(a, b, c) __builtin_amdgcn_mfma_f32_16x16x32_bf16((a), (b), (c), 0, 0, 0)

__device__ inline unsigned short bf16_bits(float f) {
    __bf16 h = (__bf16)f;   // RNE
    return __builtin_bit_cast(unsigned short, h);
}

// ---------------- merged prep kernel ----------------
// blocks [0,256): centers f32 -> bf16 in CHUNK-MAJOR layout per 64-row tile:
//   chunk q = kc*64 + crow (kc = 16B k-chunk 0..31, crow = row-in-tile 0..63)
//   cbf_byte = t*32768 + q*16.  Main kernel's linear global_load_lds then
//   yields conflict-free lane-linear GEMM1 reads (verified R5: 5.2M -> 1.0M).
// Also a2 = 2*alpha, aal = alpha, acs = alpha*csq  (alpha = 1/(2s^2+eps)).
// blocks [256,320): W [64,1024] f32 -> bf16 row-major.
__global__ __launch_bounds__(256) void prep(const float* __restrict__ cent,
                                            const float* __restrict__ sigma,
                                            const float* __restrict__ w,
                                            unsigned short* __restrict__ cbf,
                                            float* __restrict__ a2,
                                            float* __restrict__ aal,
                                            float* __restrict__ acs,
                                            unsigned short* __restrict__ wbf) {
    const int bid = blockIdx.x;
    if (bid < 256) {
        const int wid = threadIdx.x >> 6, lane = threadIdx.x & 63;
        const int c = bid * 4 + wid;
        float4 v = ((const float4*)cent)[(size_t)c * 64 + lane];
        u16x4 o;
        o[0] = bf16_bits(v.x); o[1] = bf16_bits(v.y);
        o[2] = bf16_bits(v.z); o[3] = bf16_bits(v.w);
        const int t = c >> 6, crow = c & 63, kc = lane >> 1;
        *(u16x4*)((char*)cbf + t * 32768 + (kc * 64 + crow) * 16 + (lane & 1) * 8) = o;
        float ss = v.x * v.x + v.y * v.y + v.z * v.z + v.w * v.w;
        #pragma unroll
        for (int off = 32; off; off >>= 1) ss += __shfl_down(ss, off);
        if (lane == 0) {
            float s = sigma[c];
            float al = 1.0f / (2.0f * s * s + 1e-8f);
            a2[c] = 2.0f * al;
            aal[c] = al;
            acs[c] = al * ss;
        }
    } else {
        const int o = bid - 256;
        float4 v = ((const float4*)w)[(size_t)o * 256 + threadIdx.x];
        u16x4 u;
        u[0] = bf16_bits(v.x); u[1] = bf16_bits(v.y);
        u[2] = bf16_bits(v.z); u[3] = bf16_bits(v.w);
        *(u16x4*)(wbf + (size_t)o * NC + threadIdx.x * 4) = u;
    }
}

// ---------------- main fused kernel ----------------
// grid 1024, block 256 (4 waves x 16 rows). 16 C-tiles of 64.
// Serial stage (R3's measured-better order); occupancy lever: 40KB LDS +
// launch_bounds(256,4) -> target 4 blocks/CU = 16 waves/CU.
__global__ __launch_bounds__(256, 4) void rbf_main(
    const float* __restrict__ x,
    const __bf16* __restrict__ cbf, const float* __restrict__ a2,
    const float* __restrict__ aal, const float* __restrict__ acs,
    const __bf16* __restrict__ wbf,
    const float* __restrict__ bias, float* __restrict__ out) {

    __shared__ __bf16 cent_lds[BC * DIM];      // 32KB, chunk-major [kc][crow]
    __shared__ __bf16 rbf_lds[4][WROWS * BC];  // 2KB/wave, chunk-major [cc][n]

    const int tid  = threadIdx.x;
    const int wid  = tid >> 6;
    const int lane = tid & 63;
    const int l15  = lane & 15;
    const int hi   = lane >> 4;          // 0..3

    const int rowbase = blockIdx.x * BN + wid * WROWS;

    // ---- x fragments straight from f32 global; xsq in-register ----
    // xf[ks]: row = rowbase + l15, k = ks*32 + hi*8 .. +8
    bf16x8 xf[8];
    float xsqv;
    {
        const float* xr = x + (size_t)(rowbase + l15) * DIM;
        float ss = 0.f;
        #pragma unroll
        for (int ks = 0; ks < 8; ++ks) {
            float4 a = *(const float4*)(xr + ks * 32 + hi * 8);
            float4 b = *(const float4*)(xr + ks * 32 + hi * 8 + 4);
            bf16x8 f;
            f[0] = (__bf16)a.x; f[1] = (__bf16)a.y; f[2] = (__bf16)a.z; f[3] = (__bf16)a.w;
            f[4] = (__bf16)b.x; f[5] = (__bf16)b.y; f[6] = (__bf16)b.z; f[7] = (__bf16)b.w;
            xf[ks] = f;
            ss += a.x * a.x + a.y * a.y + a.z * a.z + a.w * a.w;
            ss += b.x * b.x + b.y * b.y + b.z * b.z + b.w * b.w;
        }
        // lanes sharing l15 (hi=0..3) hold disjoint 64-elem k-slices of the row
        ss += __shfl_xor(ss, 16);
        ss += __shfl_xor(ss, 32);
        xsqv = ss;
    }

    float bo[4];
    #pragma unroll
    for (int of = 0; of < 4; ++of) bo[of] = bias[of * 16 + l15];

    f32x4 oacc[4];
    #pragma unroll
    for (int of = 0; of < 4; ++of) {
        f32x4 z = {0.f, 0.f, 0.f, 0.f};
        oacc[of] = z;
    }

    #pragma unroll 1
    for (int t = 0; t < NTILE; ++t) {
        {   // stage tile t: 2048 16B chunks; linear LDS dest = wave base + lane*16
            const char* src = (const char*)cbf + (size_t)t * 32768
                              + (size_t)(wid * 64 + lane) * 16;
            char* dstb = (char*)cent_lds + (wid * 64) * 16;
            #pragma unroll
            for (int i = 0; i < 8; ++i) {
                __builtin_amdgcn_global_load_lds(
                    (const __attribute__((address_space(1))) uint32_t*)(src + i * 4096),
                    (__attribute__((address_space(3))) uint32_t*)(dstb + i * 4096), 16, 0, 0);
            }
        }
        asm volatile("s_waitcnt vmcnt(0)" ::: "memory");
        __syncthreads();   // tile staged, all waves' prior reads done

        // ---- GEMM1 (swapped): S^T[64c][16n] = centers_tile . x^T ----
        // cent read: chunk (ks*4+hi)*64 + c4*16 + l15 -> lane-linear, conflict-free
        f32x4 st[4];
        #pragma unroll
        for (int c4 = 0; c4 < 4; ++c4) {
            f32x4 z = {0.f, 0.f, 0.f, 0.f};
            st[c4] = z;
        }
        #pragma unroll
        for (int ks = 0; ks < 8; ++ks) {
            bf16x8 cf[4];
            #pragma unroll
            for (int c4 = 0; c4 < 4; ++c4)
                cf[c4] = *(const bf16x8*)((const char*)cent_lds
                          + ((ks * 4 + hi) * 64 + c4 * 16 + l15) * 16);
            #pragma unroll
            for (int c4 = 0; c4 < 4; ++c4)
                st[c4] = MFMA16(cf[c4], xf[ks], st[c4]);
        }

        // ---- rbf = exp(fma(2a, S, -a*xsq - a*csq)), pack bf16, wave-local stage ----
        // rbf_lds chunk-major [cc][n], cc = c/8: write 8B at
        // ((c4*2 + hi/2)*16 + l15)*16 + (hi&1)*8
        char* const rbase = (char*)&rbf_lds[wid][0];
        #pragma unroll
        for (int c4 = 0; c4 < 4; ++c4) {
            const int cg = t * BC + c4 * 16 + hi * 4;
            const f32x4 a24 = *(const f32x4*)(a2 + cg);
            const f32x4 al4 = *(const f32x4*)(aal + cg);
            const f32x4 ac4 = *(const f32x4*)(acs + cg);
            const f32x4 v = st[c4];
            float p0 = __expf(a24[0] * v[0] - al4[0] * xsqv - ac4[0]);
            float p1 = __expf(a24[1] * v[1] - al4[1] * xsqv - ac4[1]);
            float p2 = __expf(a24[2] * v[2] - al4[2] * xsqv - ac4[2]);
            float p3 = __expf(a24[3] * v[3] - al4[3] * xsqv - ac4[3]);
            u32x2 wv;
            wv[0] = (unsigned)bf16_bits(p0) | ((unsigned)bf16_bits(p1) << 16);
            wv[1] = (unsigned)bf16_bits(p2) | ((unsigned)bf16_bits(p3) << 16);
            const int byte = ((c4 * 2 + (hi >> 1)) * 16 + l15) * 16 + (hi & 1) * 8;
            *(u32x2*)(rbase + byte) = wv;
        }

        // ---- GEMM2: out[16n][64o] += rbf[16n][64c] . Wt[64c][64o] ----
        // pa read: chunk (cs*4+hi)*16 + n -> lane-linear, conflict-free
        #pragma unroll
        for (int cs = 0; cs < 2; ++cs) {
            const bf16x8 pa = *(const bf16x8*)(rbase + ((cs * 4 + hi) * 16 + l15) * 16);
            #pragma unroll
            for (int of = 0; of < 4; ++of) {
                const bf16x8 wb = *(const bf16x8*)(wbf + (size_t)(of * 16 + l15) * NC
                                                   + t * BC + cs * 32 + hi * 8);
                oacc[of] = MFMA16(pa, wb, oacc[of]);
            }
        }

        __syncthreads();   // all waves done with cent_lds before next stage
    }

    // epilogue: D layout row = hi*4 + r (n), col = l15 (o)
    #pragma unroll
    for (int of = 0; of < 4; ++of)
        #pragma unroll
        for (int r = 0; r < 4; ++r) {
            const int n = rowbase + hi * 4 + r;
            out[(size_t)n * NO + of * 16 + l15] = oacc[of][r] + bo[of];
        }
}

// ---------------- launcher ----------------
extern "C" void kernel_launch(void* const* d_in, const int* in_sizes, int n_in,
                              void* d_out, int out_size, void* d_ws, size_t ws_size,
                              hipStream_t stream) {
    const float* x     = (const float*)d_in[0];
    const float* cent  = (const float*)d_in[1];
    const float* sigma = (const float*)d_in[2];
    const float* W     = (const float*)d_in[3];
    const float* b     = (const float*)d_in[4];
    float* out = (float*)d_out;

    char* ws = (char*)d_ws;
    unsigned short* cbf  = (unsigned short*)(ws + 0);        //   524,288 B
    float*          a2p  = (float*)(ws + 524288);            //     4,096 B
    float*          aalp = (float*)(ws + 528384);            //     4,096 B
    float*          acsp = (float*)(ws + 532480);            //     4,096 B
    unsigned short* wbf  = (unsigned short*)(ws + 536576);   //   131,072 B

    prep<<<320, 256, 0, stream>>>(cent, sigma, W, cbf, a2p, aalp, acsp, wbf);
    rbf_main<<<NROWS / BN, 256, 0, stream>>>(
        x, (const __bf16*)cbf, a2p, aalp, acsp, (const __bf16*)wbf, b, out);
}

// Round 7
// 169.613 us; speedup vs baseline: 1.1838x; 1.1838x over previous
//
#include <hip/hip_runtime.h>
#include <stdint.h>

#define NROWS 65536
#define DIM   256
#define NC    1024
#define NO    64

#define BN    128          // rows per block (4 waves x 32 rows)
#define WROWS 32           // rows per wave
#define BC    128          // centers per tile (R7: was 64 -> halves convoy count)
#define NTILE (NC / BC)    // 8

using bf16x8 = __bf16 __attribute__((ext_vector_type(8)));
using f32x4  = float __attribute__((ext_vector_type(4)));
using u16x4  = unsigned short __attribute__((ext_vector_type(4)));
using u32x2  = unsigned int __attribute__((ext_vector_type(2)));

#define MFMA16(a, b, c) __builtin_amdgcn_mfma_f32_16x16x32_bf16((a), (b), (c), 0, 0, 0)

__device__ inline unsigned short bf16_bits(float f) {
    __bf16 h = (__bf16)f;   // RNE
    return __builtin_bit_cast(unsigned short, h);
}

// ---------------- merged prep kernel ----------------
// blocks [0,256): centers f32 -> bf16, CHUNK-MAJOR per 128-row tile:
//   tile t = c>>7, crow = c&127, kc = k>>3 (16B k-chunk 0..31)
//   byte = t*65536 + (kc*128 + crow)*16 + (k&7)*2
// Main kernel's linear global_load_lds then yields conflict-free lane-linear
// GEMM1 reads (chunk-major verified R5/R6: conflicts 5.2M -> 1.0M).
// Also a2 = 2*alpha, acs = alpha*csq (alpha = 1/(2s^2+eps)); exp arg is
// a2*(S - xsq/2) - acs, so no separate alpha array needed.
// blocks [256,320): W [64,1024] f32 -> bf16 row-major.
__global__ __launch_bounds__(256) void prep(const float* __restrict__ cent,
                                            const float* __restrict__ sigma,
                                            const float* __restrict__ w,
                                            unsigned short* __restrict__ cbf,
                                            float* __restrict__ a2,
                                            float* __restrict__ acs,
                                            unsigned short* __restrict__ wbf) {
    const int bid = blockIdx.x;
    if (bid < 256) {
        const int wid = threadIdx.x >> 6, lane = threadIdx.x & 63;
        const int c = bid * 4 + wid;
        float4 v = ((const float4*)cent)[(size_t)c * 64 + lane];
        u16x4 o;
        o[0] = bf16_bits(v.x); o[1] = bf16_bits(v.y);
        o[2] = bf16_bits(v.z); o[3] = bf16_bits(v.w);
        const int t = c >> 7, crow = c & 127, kc = lane >> 1;
        *(u16x4*)((char*)cbf + t * 65536 + (kc * 128 + crow) * 16 + (lane & 1) * 8) = o;
        float ss = v.x * v.x + v.y * v.y + v.z * v.z + v.w * v.w;
        #pragma unroll
        for (int off = 32; off; off >>= 1) ss += __shfl_down(ss, off);
        if (lane == 0) {
            float s = sigma[c];
            float al = 1.0f / (2.0f * s * s + 1e-8f);
            a2[c] = 2.0f * al;
            acs[c] = al * ss;
        }
    } else {
        const int o = bid - 256;
        float4 v = ((const float4*)w)[(size_t)o * 256 + threadIdx.x];
        u16x4 u;
        u[0] = bf16_bits(v.x); u[1] = bf16_bits(v.y);
        u[2] = bf16_bits(v.z); u[3] = bf16_bits(v.w);
        *(u16x4*)(wbf + (size_t)o * NC + threadIdx.x * 4) = u;
    }
}

// ---------------- main fused kernel ----------------
// grid 512, block 256 (4 waves x 32 rows). 8 C-tiles of 128 (R3's serial
// stage->drain->barrier->compute skeleton, half as many convoys).
// LDS 64KB cent + 16KB rbf = 80KB -> 2 blocks/CU (grid-capped anyway).
__global__ __launch_bounds__(256, 2) void rbf_main(
    const float* __restrict__ x,
    const __bf16* __restrict__ cbf, const float* __restrict__ a2,
    const float* __restrict__ acs, const __bf16* __restrict__ wbf,
    const float* __restrict__ bias, float* __restrict__ out) {

    __shared__ __bf16 cent_lds[BC * DIM];      // 64KB, chunk-major [kc][crow]
    __shared__ __bf16 rbf_lds[4][WROWS * 64];  // 4KB/wave (reused per 64c half)

    const int tid  = threadIdx.x;
    const int wid  = tid >> 6;
    const int lane = tid & 63;
    const int l15  = lane & 15;
    const int hi   = lane >> 4;          // 0..3

    const int rowbase = blockIdx.x * BN + wid * WROWS;

    // ---- x fragments straight from f32 global; xsq in-register ----
    // xf[nf][ks]: row = rowbase + nf*16 + l15, k = ks*32 + hi*8 .. +8
    bf16x8 xf[2][8];
    float hxsq[2];                        // xsq/2
    #pragma unroll
    for (int nf = 0; nf < 2; ++nf) {
        const float* xr = x + (size_t)(rowbase + nf * 16 + l15) * DIM;
        float ss = 0.f;
        #pragma unroll
        for (int ks = 0; ks < 8; ++ks) {
            float4 a = *(const float4*)(xr + ks * 32 + hi * 8);
            float4 b = *(const float4*)(xr + ks * 32 + hi * 8 + 4);
            bf16x8 f;
            f[0] = (__bf16)a.x; f[1] = (__bf16)a.y; f[2] = (__bf16)a.z; f[3] = (__bf16)a.w;
            f[4] = (__bf16)b.x; f[5] = (__bf16)b.y; f[6] = (__bf16)b.z; f[7] = (__bf16)b.w;
            xf[nf][ks] = f;
            ss += a.x * a.x + a.y * a.y + a.z * a.z + a.w * a.w;
            ss += b.x * b.x + b.y * b.y + b.z * b.z + b.w * b.w;
        }
        ss += __shfl_xor(ss, 16);
        ss += __shfl_xor(ss, 32);
        hxsq[nf] = 0.5f * ss;
    }

    float bo[4];
    #pragma unroll
    for (int of = 0; of < 4; ++of) bo[of] = bias[of * 16 + l15];

    f32x4 oacc[2][4];
    #pragma unroll
    for (int nf = 0; nf < 2; ++nf)
        #pragma unroll
        for (int of = 0; of < 4; ++of) {
            f32x4 z = {0.f, 0.f, 0.f, 0.f};
            oacc[nf][of] = z;
        }

    #pragma unroll 1
    for (int t = 0; t < NTILE; ++t) {
        __syncthreads();   // all waves done reading cent_lds from prior tile
        {   // stage tile t: 4096 16B chunks; linear LDS dest = wave base + lane*16
            const char* src = (const char*)cbf + (size_t)t * 65536
                              + (size_t)(wid * 64 + lane) * 16;
            char* dstb = (char*)cent_lds + (wid * 64) * 16;
            #pragma unroll
            for (int i = 0; i < 16; ++i) {
                __builtin_amdgcn_global_load_lds(
                    (const __attribute__((address_space(1))) uint32_t*)(src + i * 4096),
                    (__attribute__((address_space(3))) uint32_t*)(dstb + i * 4096), 16, 0, 0);
            }
        }
        asm volatile("s_waitcnt vmcnt(0)" ::: "memory");
        __syncthreads();   // tile staged

        // ---- GEMM1 (swapped): S^T[128c][32n] = centers_tile . x^T ----
        // cf read: chunk (ks*4+hi)*128 + c4*16 + l15 -> lane-linear, conflict-free
        f32x4 st[8][2];
        #pragma unroll
        for (int c4 = 0; c4 < 8; ++c4)
            #pragma unroll
            for (int nf = 0; nf < 2; ++nf) {
                f32x4 z = {0.f, 0.f, 0.f, 0.f};
                st[c4][nf] = z;
            }
        #pragma unroll
        for (int ks = 0; ks < 8; ++ks) {
            bf16x8 cf[8];
            #pragma unroll
            for (int c4 = 0; c4 < 8; ++c4)
                cf[c4] = *(const bf16x8*)((const char*)cent_lds
                          + ((ks * 4 + hi) * 128 + c4 * 16 + l15) * 16);
            #pragma unroll
            for (int c4 = 0; c4 < 8; ++c4)
                #pragma unroll
                for (int nf = 0; nf < 2; ++nf)
                    st[c4][nf] = MFMA16(cf[c4], xf[nf][ks], st[c4][nf]);
        }

        // ---- two 64c halves: rbf pack -> wave-local 4KB -> GEMM2 ----
        char* const rbase = (char*)&rbf_lds[wid][0];
        #pragma unroll
        for (int h = 0; h < 2; ++h) {
            // rbf = exp(a2*(S - xsq/2) - acs), pack bf16, wave-local stage
            #pragma unroll
            for (int c4h = 0; c4h < 4; ++c4h) {
                const int c4 = h * 4 + c4h;
                const int cg = t * BC + c4 * 16 + hi * 4;
                const f32x4 a24 = *(const f32x4*)(a2 + cg);
                const f32x4 ac4 = *(const f32x4*)(acs + cg);
                #pragma unroll
                for (int nf = 0; nf < 2; ++nf) {
                    const f32x4 v = st[c4][nf];
                    float p0 = __expf(a24[0] * (v[0] - hxsq[nf]) - ac4[0]);
                    float p1 = __expf(a24[1] * (v[1] - hxsq[nf]) - ac4[1]);
                    float p2 = __expf(a24[2] * (v[2] - hxsq[nf]) - ac4[2]);
                    float p3 = __expf(a24[3] * (v[3] - hxsq[nf]) - ac4[3]);
                    u32x2 wv;
                    wv[0] = (unsigned)bf16_bits(p0) | ((unsigned)bf16_bits(p1) << 16);
                    wv[1] = (unsigned)bf16_bits(p2) | ((unsigned)bf16_bits(p3) << 16);
                    const int byte = ((c4h * 2 + (hi >> 1)) * 32 + nf * 16 + l15) * 16
                                     + (hi & 1) * 8;
                    *(u32x2*)(rbase + byte) = wv;
                }
            }
            // GEMM2: oacc += rbf[32n][64c_half] . Wt[64c_half][64o]
            #pragma unroll
            for (int cs = 0; cs < 2; ++cs) {
                bf16x8 pa[2];
                #pragma unroll
                for (int nf = 0; nf < 2; ++nf)
                    pa[nf] = *(const bf16x8*)(rbase
                              + ((cs * 4 + hi) * 32 + nf * 16 + l15) * 16);
                #pragma unroll
                for (int of = 0; of < 4; ++of) {
                    const bf16x8 wb = *(const bf16x8*)(wbf
                        + (size_t)(of * 16 + l15) * NC + t * BC + h * 64 + cs * 32 + hi * 8);
                    #pragma unroll
                    for (int nf = 0; nf < 2; ++nf)
                        oacc[nf][of] = MFMA16(pa[nf], wb, oacc[nf][of]);
                }
            }
        }
    }

    // epilogue: D layout row = hi*4 + r (n), col = l15 (o)
    #pragma unroll
    for (int nf = 0; nf < 2; ++nf)
        #pragma unroll
        for (int of = 0; of < 4; ++of)
            #pragma unroll
            for (int r = 0; r < 4; ++r) {
                const int n = rowbase + nf * 16 + hi * 4 + r;
                out[(size_t)n * NO + of * 16 + l15] = oacc[nf][of][r] + bo[of];
            }
}

// ---------------- launcher ----------------
extern "C" void kernel_launch(void* const* d_in, const int* in_sizes, int n_in,
                              void* d_out, int out_size, void* d_ws, size_t ws_size,
                              hipStream_t stream) {
    const float* x     = (const float*)d_in[0];
    const float* cent  = (const float*)d_in[1];
    const float* sigma = (const float*)d_in[2];
    const float* W     = (const float*)d_in[3];
    const float* b     = (const float*)d_in[4];
    float* out = (float*)d_out;

    char* ws = (char*)d_ws;
    unsigned short* cbf  = (unsigned short*)(ws + 0);        //   524,288 B
    float*          a2p  = (float*)(ws + 524288);            //     4,096 B
    float*          acsp = (float*)(ws + 528384);            //     4,096 B
    unsigned short* wbf  = (unsigned short*)(ws + 532480);   //   131,072 B

    prep<<<320, 256, 0, stream>>>(cent, sigma, W, cbf, a2p, acsp, wbf);
    rbf_main<<<NROWS / BN, 256, 0, stream>>>(
        x, (const __bf16*)cbf, a2p, acsp, (const __bf16*)wbf, b, out);
}

// Round 8
// 165.491 us; speedup vs baseline: 1.2133x; 1.0249x over previous
//
#include <hip/hip_runtime.h>
#include <stdint.h>

#define NROWS 65536
#define DIM   256
#define NC    1024
#define NO    64

#define BN    128          // rows per block (4 waves x 32 rows)
#define WROWS 32           // rows per wave
#define BC    64           // centers per tile (R3 best)
#define NTILE (NC / BC)    // 16

using bf16x8 = __bf16 __attribute__((ext_vector_type(8)));
using f32x4  = float __attribute__((ext_vector_type(4)));
using u16x4  = unsigned short __attribute__((ext_vector_type(4)));
using u32x2  = unsigned int __attribute__((ext_vector_type(2)));

#define MFMA16(a, b, c) __builtin_amdgcn_mfma_f32_16x16x32_bf16((a), (b), (c), 0, 0, 0)

__device__ inline unsigned short bf16_bits(float f) {
    __bf16 h = (__bf16)f;   // RNE
    return __builtin_bit_cast(unsigned short, h);
}

// ---------------- merged prep kernel ----------------
// blocks [0,256): centers f32 -> bf16, CHUNK-MAJOR per 64-row tile:
//   chunk q = kc*64 + crow (kc = 16B k-chunk 0..31, crow = row-in-tile 0..63)
//   byte = t*32768 + q*16.  Main kernel's linear global_load_lds then yields
//   conflict-free lane-linear GEMM1 reads (verified R5-R7: 5.2M -> 1.0M).
// Also a2 = 2*alpha, acs = alpha*csq (alpha = 1/(2s^2+eps)); exp arg is
// a2*(S - xsq/2) - acs.
// blocks [256,320): W [64,1024] f32 -> bf16 row-major.
__global__ __launch_bounds__(256) void prep(const float* __restrict__ cent,
                                            const float* __restrict__ sigma,
                                            const float* __restrict__ w,
                                            unsigned short* __restrict__ cbf,
                                            float* __restrict__ a2,
                                            float* __restrict__ acs,
                                            unsigned short* __restrict__ wbf) {
    const int bid = blockIdx.x;
    if (bid < 256) {
        const int wid = threadIdx.x >> 6, lane = threadIdx.x & 63;
        const int c = bid * 4 + wid;
        float4 v = ((const float4*)cent)[(size_t)c * 64 + lane];
        u16x4 o;
        o[0] = bf16_bits(v.x); o[1] = bf16_bits(v.y);
        o[2] = bf16_bits(v.z); o[3] = bf16_bits(v.w);
        const int t = c >> 6, crow = c & 63, kc = lane >> 1;
        *(u16x4*)((char*)cbf + t * 32768 + (kc * 64 + crow) * 16 + (lane & 1) * 8) = o;
        float ss = v.x * v.x + v.y * v.y + v.z * v.z + v.w * v.w;
        #pragma unroll
        for (int off = 32; off; off >>= 1) ss += __shfl_down(ss, off);
        if (lane == 0) {
            float s = sigma[c];
            float al = 1.0f / (2.0f * s * s + 1e-8f);
            a2[c] = 2.0f * al;
            acs[c] = al * ss;
        }
    } else {
        const int o = bid - 256;
        float4 v = ((const float4*)w)[(size_t)o * 256 + threadIdx.x];
        u16x4 u;
        u[0] = bf16_bits(v.x); u[1] = bf16_bits(v.y);
        u[2] = bf16_bits(v.z); u[3] = bf16_bits(v.w);
        *(u16x4*)(wbf + (size_t)o * NC + threadIdx.x * 4) = u;
    }
}

// ---------------- main fused kernel ----------------
// grid 512, block 256 (4 waves x 32 rows). 16 C-tiles of 64.
// R8 dataflow: c4-outer GEMM1 with per-chunk exp (VALU hides under next
// chunk's MFMAs); stage(t+1) issued after the GEMM1 barrier so the drain
// hides under GEMM2 (which never touches cent_lds).
__global__ __launch_bounds__(256, 2) void rbf_main(
    const float* __restrict__ x,
    const __bf16* __restrict__ cbf, const float* __restrict__ a2,
    const float* __restrict__ acs, const __bf16* __restrict__ wbf,
    const float* __restrict__ bias, float* __restrict__ out) {

    __shared__ __bf16 cent_lds[BC * DIM];      // 32KB, chunk-major [kc][crow]
    __shared__ __bf16 rbf_lds[4][WROWS * BC];  // 4KB/wave, chunk-major [cc][n]

    const int tid  = threadIdx.x;
    const int wid  = tid >> 6;
    const int lane = tid & 63;
    const int l15  = lane & 15;
    const int hi   = lane >> 4;          // 0..3

    const int rowbase = blockIdx.x * BN + wid * WROWS;

    // stage tile t: 2048 16B chunks; linear LDS dest = wave base + lane*16
    auto stage = [&](int t) {
        const char* src = (const char*)cbf + (size_t)t * 32768
                          + (size_t)(wid * 64 + lane) * 16;
        char* dstb = (char*)cent_lds + (wid * 64) * 16;
        #pragma unroll
        for (int i = 0; i < 8; ++i) {
            __builtin_amdgcn_global_load_lds(
                (const __attribute__((address_space(1))) uint32_t*)(src + i * 4096),
                (__attribute__((address_space(3))) uint32_t*)(dstb + i * 4096), 16, 0, 0);
        }
    };

    stage(0);   // latency covered by the x-load/convert prologue below

    // ---- x fragments straight from f32 global; xsq in-register ----
    // xf[nf][ks]: row = rowbase + nf*16 + l15, k = ks*32 + hi*8 .. +8
    bf16x8 xf[2][8];
    float hxsq[2];                        // xsq/2
    #pragma unroll
    for (int nf = 0; nf < 2; ++nf) {
        const float* xr = x + (size_t)(rowbase + nf * 16 + l15) * DIM;
        float ss = 0.f;
        #pragma unroll
        for (int ks = 0; ks < 8; ++ks) {
            float4 a = *(const float4*)(xr + ks * 32 + hi * 8);
            float4 b = *(const float4*)(xr + ks * 32 + hi * 8 + 4);
            bf16x8 f;
            f[0] = (__bf16)a.x; f[1] = (__bf16)a.y; f[2] = (__bf16)a.z; f[3] = (__bf16)a.w;
            f[4] = (__bf16)b.x; f[5] = (__bf16)b.y; f[6] = (__bf16)b.z; f[7] = (__bf16)b.w;
            xf[nf][ks] = f;
            ss += a.x * a.x + a.y * a.y + a.z * a.z + a.w * a.w;
            ss += b.x * b.x + b.y * b.y + b.z * b.z + b.w * b.w;
        }
        ss += __shfl_xor(ss, 16);
        ss += __shfl_xor(ss, 32);
        hxsq[nf] = 0.5f * ss;
    }

    float bo[4];
    #pragma unroll
    for (int of = 0; of < 4; ++of) bo[of] = bias[of * 16 + l15];

    f32x4 oacc[2][4];
    #pragma unroll
    for (int nf = 0; nf < 2; ++nf)
        #pragma unroll
        for (int of = 0; of < 4; ++of) {
            f32x4 z = {0.f, 0.f, 0.f, 0.f};
            oacc[nf][of] = z;
        }

    asm volatile("s_waitcnt vmcnt(0)" ::: "memory");
    __syncthreads();   // tile 0 staged

    char* const rbase = (char*)&rbf_lds[wid][0];

    #pragma unroll 1
    for (int t = 0; t < NTILE; ++t) {
        // ---- GEMM1, c4-outer: 16-center chunk -> immediate exp/pack/write.
        // Chunk c4+1's cf reads + MFMAs are independent of chunk c4's exp,
        // so VALU (exp) overlaps the matrix pipe after unrolling.
        #pragma unroll
        for (int c4 = 0; c4 < 4; ++c4) {
            bf16x8 cf[8];
            #pragma unroll
            for (int ks = 0; ks < 8; ++ks)
                cf[ks] = *(const bf16x8*)((const char*)cent_lds
                          + ((ks * 4 + hi) * 64 + c4 * 16 + l15) * 16);
            f32x4 s0 = {0.f, 0.f, 0.f, 0.f};
            f32x4 s1 = {0.f, 0.f, 0.f, 0.f};
            #pragma unroll
            for (int ks = 0; ks < 8; ++ks) {
                s0 = MFMA16(cf[ks], xf[0][ks], s0);
                s1 = MFMA16(cf[ks], xf[1][ks], s1);
            }
            const int cg = t * BC + c4 * 16 + hi * 4;
            const f32x4 a24 = *(const f32x4*)(a2 + cg);
            const f32x4 ac4 = *(const f32x4*)(acs + cg);
            const int cc0 = (c4 * 2 + (hi >> 1)) * 32;
            const int sub = (hi & 1) * 8;
            {   // nf = 0
                float p0 = __expf(a24[0] * (s0[0] - hxsq[0]) - ac4[0]);
                float p1 = __expf(a24[1] * (s0[1] - hxsq[0]) - ac4[1]);
                float p2 = __expf(a24[2] * (s0[2] - hxsq[0]) - ac4[2]);
                float p3 = __expf(a24[3] * (s0[3] - hxsq[0]) - ac4[3]);
                u32x2 wv;
                wv[0] = (unsigned)bf16_bits(p0) | ((unsigned)bf16_bits(p1) << 16);
                wv[1] = (unsigned)bf16_bits(p2) | ((unsigned)bf16_bits(p3) << 16);
                *(u32x2*)(rbase + (cc0 + l15) * 16 + sub) = wv;
            }
            {   // nf = 1
                float p0 = __expf(a24[0] * (s1[0] - hxsq[1]) - ac4[0]);
                float p1 = __expf(a24[1] * (s1[1] - hxsq[1]) - ac4[1]);
                float p2 = __expf(a24[2] * (s1[2] - hxsq[1]) - ac4[2]);
                float p3 = __expf(a24[3] * (s1[3] - hxsq[1]) - ac4[3]);
                u32x2 wv;
                wv[0] = (unsigned)bf16_bits(p0) | ((unsigned)bf16_bits(p1) << 16);
                wv[1] = (unsigned)bf16_bits(p2) | ((unsigned)bf16_bits(p3) << 16);
                *(u32x2*)(rbase + (cc0 + 16 + l15) * 16 + sub) = wv;
            }
        }

        __syncthreads();               // all waves done reading cent_lds
        if (t + 1 < NTILE) stage(t + 1);   // drain hides under GEMM2 below

        // ---- GEMM2: out[32n][64o] += rbf[32n][64c] . Wt[64c][64o] ----
        // touches only rbf_lds (wave-local) + W (L2) -> safe under staging
        #pragma unroll
        for (int cs = 0; cs < 2; ++cs) {
            bf16x8 pa[2];
            #pragma unroll
            for (int nf = 0; nf < 2; ++nf)
                pa[nf] = *(const bf16x8*)(rbase
                          + ((cs * 4 + hi) * 32 + nf * 16 + l15) * 16);
            #pragma unroll
            for (int of = 0; of < 4; ++of) {
                const bf16x8 wb = *(const bf16x8*)(wbf + (size_t)(of * 16 + l15) * NC
                                                   + t * BC + cs * 32 + hi * 8);
                #pragma unroll
                for (int nf = 0; nf < 2; ++nf)
                    oacc[nf][of] = MFMA16(pa[nf], wb, oacc[nf][of]);
            }
        }

        asm volatile("s_waitcnt vmcnt(0)" ::: "memory");
        __syncthreads();               // tile t+1 staged & visible
    }

    // epilogue: D layout row = hi*4 + r (n), col = l15 (o)
    #pragma unroll
    for (int nf = 0; nf < 2; ++nf)
        #pragma unroll
        for (int of = 0; of < 4; ++of)
            #pragma unroll
            for (int r = 0; r < 4; ++r) {
                const int n = rowbase + nf * 16 + hi * 4 + r;
                out[(size_t)n * NO + of * 16 + l15] = oacc[nf][of][r] + bo[of];
            }
}

// ---------------- launcher ----------------
extern "C" void kernel_launch(void* const* d_in, const int* in_sizes, int n_in,
                              void* d_out, int out_size, void* d_ws, size_t ws_size,
                              hipStream_t stream) {
    const float* x     = (const float*)d_in[0];
    const float* cent  = (const float*)d_in[1];
    const float* sigma = (const float*)d_in[2];
    const float* W     = (const float*)d_in[3];
    const float* b     = (const float*)d_in[4];
    float* out = (float*)d_out;

    char* ws = (char*)d_ws;
    unsigned short* cbf  = (unsigned short*)(ws + 0);        //   524,288 B
    float*          a2p  = (float*)(ws + 524288);            //     4,096 B
    float*          acsp = (float*)(ws + 528384);            //     4,096 B
    unsigned short* wbf  = (unsigned short*)(ws + 532480);   //   131,072 B

    prep<<<320, 256, 0, stream>>>(cent, sigma, W, cbf, a2p, acsp, wbf);
    rbf_main<<<NROWS / BN, 256, 0, stream>>>(
        x, (const __bf16*)cbf, a2p, acsp, (const __bf16*)wbf, b, out);
}